// Round 12
// baseline (1900.602 us; speedup 1.0000x reference)
//
#include <hip/hip_runtime.h>
#include <hip/hip_bf16.h>

#define N_NODE   100000
#define N_EDGE   1600000
#define IN_DIM   128
#define HID1     64
#define HID2     64
#define OUT_DIM  32
#define NUM_GRAPHS 256

#define NBUCK    782            // ceil(100000/128) node buckets of 128
#define BBLK     500            // binning blocks
#define EPB      3200           // edges per binning block (500*3200 = 1.6M exact)

typedef unsigned int uint;
typedef unsigned char uchar;
typedef unsigned short ushort_t;
typedef short bf16x8 __attribute__((ext_vector_type(8)));
typedef float f32x4 __attribute__((ext_vector_type(4)));

__device__ __forceinline__ float bflo(uint p) { return __uint_as_float(p << 16); }
__device__ __forceinline__ float bfhi(uint p) { return __uint_as_float(p & 0xFFFF0000u); }
__device__ __forceinline__ uint bfpack(float a, float b) {
    uint ua = __float_as_uint(a), ub = __float_as_uint(b);
    ua = (ua + 0x7FFFu + ((ua >> 16) & 1u)) >> 16;
    ub = (ub + 0x7FFFu + ((ub >> 16) & 1u)) & 0xFFFF0000u;
    return ua | ub;
}
__device__ __forceinline__ ushort_t bf16r(float f) {
    uint ua = __float_as_uint(f);
    return (ushort_t)((ua + 0x7FFFu + ((ua >> 16) & 1u)) >> 16);
}

// block-wide exclusive scan of hist[0..NBUCK) in LDS; hist[NBUCK] = total
__device__ __forceinline__ void scan_lds(int* hist, int t, int lane, int wave, int* sW) {
    int carry = 0;
    for (int k = 0; k < 4; ++k) {
        int idx = k * 256 + t;
        int v = (idx < NBUCK) ? hist[idx] : 0;
        int inc = v;
        #pragma unroll
        for (int o = 1; o < 64; o <<= 1) { int n = __shfl_up(inc, o); if (lane >= o) inc += n; }
        if (lane == 63) sW[wave] = inc;
        __syncthreads();
        int wOff = 0;
        for (int w = 0; w < wave; ++w) wOff += sW[w];
        int tot = sW[0] + sW[1] + sW[2] + sW[3];
        int excl = carry + wOff + inc - v;
        __syncthreads();
        if (idx < NBUCK) hist[idx] = excl;
        carry += tot;
        __syncthreads();
    }
    if (t == 0) hist[NBUCK] = carry;
    __syncthreads();
}

// ---------------- preprocessing: block-major binned CSR build ----------------

__global__ __launch_bounds__(256)
void k_place2(const int2* __restrict__ snd2, const int2* __restrict__ rcv2,
              int* __restrict__ localOffR, int* __restrict__ localOffS,   // [BBLK][NBUCK+1]
              uint* __restrict__ binned2, uint* __restrict__ sBin2u) {
    __shared__ int histR[NBUCK + 1];
    __shared__ int histS[NBUCK + 1];
    __shared__ int curR[NBUCK];
    __shared__ int curS[NBUCK];
    __shared__ uint bufR[EPB];
    __shared__ uint bufSu[EPB / 4];
    __shared__ int sW[4];
    const int t = threadIdx.x, blk = blockIdx.x, lane = t & 63, wave = t >> 6;
    for (int i = t; i < NBUCK + 1; i += 256) { histR[i] = 0; histS[i] = 0; }
    for (int i = t; i < NBUCK; i += 256) { curR[i] = 0; curS[i] = 0; }
    __syncthreads();
    const int base2 = blk * (EPB / 2);
    int2 rs[7], ss[7];
    #pragma unroll
    for (int i = 0; i < 7; ++i) {
        int l2 = i * 256 + t;
        if (l2 < EPB / 2) {
            rs[i] = rcv2[base2 + l2];
            ss[i] = snd2[base2 + l2];
            atomicAdd(&histR[rs[i].x >> 7], 1);
            atomicAdd(&histR[rs[i].y >> 7], 1);
            atomicAdd(&histS[ss[i].x >> 7], 1);
            atomicAdd(&histS[ss[i].y >> 7], 1);
        }
    }
    __syncthreads();
    scan_lds(histR, t, lane, wave, sW);
    scan_lds(histS, t, lane, wave, sW);
    for (int i = t; i < NBUCK + 1; i += 256) {
        localOffR[(size_t)blk * (NBUCK + 1) + i] = histR[i];
        localOffS[(size_t)blk * (NBUCK + 1) + i] = histS[i];
    }
    uchar* bufS = (uchar*)bufSu;
    #pragma unroll
    for (int i = 0; i < 7; ++i) {
        int l2 = i * 256 + t;
        if (l2 < EPB / 2) {
            int2 r = rs[i], s = ss[i];
            int b0 = r.x >> 7, b1 = r.y >> 7;
            int p0 = atomicAdd(&curR[b0], 1);
            bufR[histR[b0] + p0] = ((uint)s.x << 7) | (uint)(r.x & 127);
            int p1 = atomicAdd(&curR[b1], 1);
            bufR[histR[b1] + p1] = ((uint)s.y << 7) | (uint)(r.y & 127);
            int c0 = s.x >> 7, c1 = s.y >> 7;
            int q0 = atomicAdd(&curS[c0], 1);
            bufS[histS[c0] + q0] = (uchar)(s.x & 127);
            int q1 = atomicAdd(&curS[c1], 1);
            bufS[histS[c1] + q1] = (uchar)(s.y & 127);
        }
    }
    __syncthreads();
    for (int i = t; i < EPB; i += 256) binned2[(size_t)blk * EPB + i] = bufR[i];
    for (int i = t; i < EPB / 4; i += 256) sBin2u[(size_t)blk * (EPB / 4) + i] = bufSu[i];
}

// receiver-bucket totals from localOffR deltas
__global__ __launch_bounds__(256)
void k_totals(const int* __restrict__ localOffR, int* __restrict__ rTotal) {
    const int b = blockIdx.x, t = threadIdx.x, lane = t & 63, wave = t >> 6;
    int sum = 0;
    for (int blk = t; blk < BBLK; blk += 256) {
        size_t base = (size_t)blk * (NBUCK + 1) + b;
        sum += localOffR[base + 1] - localOffR[base];
    }
    #pragma unroll
    for (int o = 1; o < 64; o <<= 1) sum += __shfl_xor(sum, o);
    __shared__ int sw[4];
    if (lane == 0) sw[wave] = sum;
    __syncthreads();
    if (t == 0) rTotal[b] = sw[0] + sw[1] + sw[2] + sw[3];
}

// scan bucket totals -> rBase[0..NBUCK]
__global__ __launch_bounds__(256)
void k_scanB(const int* __restrict__ rTotal, int* __restrict__ rBase) {
    const int t = threadIdx.x, lane = t & 63, wave = t >> 6;
    __shared__ int sW[4];
    int carry = 0;
    for (int k = 0; k < 4; ++k) {
        int idx = k * 256 + t;
        int v = (idx < NBUCK) ? rTotal[idx] : 0;
        int inc = v;
        #pragma unroll
        for (int o = 1; o < 64; o <<= 1) { int n = __shfl_up(inc, o); if (lane >= o) inc += n; }
        if (lane == 63) sW[wave] = inc;
        __syncthreads();
        int wOff = 0;
        for (int w = 0; w < wave; ++w) wOff += sW[w];
        int tot = sW[0] + sW[1] + sW[2] + sW[3];
        int excl = carry + wOff + inc - v;
        if (idx < NBUCK) rBase[idx] = excl;
        carry += tot;
        __syncthreads();
    }
    if (t == 0) rBase[NBUCK] = carry;
}

// per-bucket: compact segments into contiguous stream (packed (s<<7)|r7) + degree histograms.
// No per-node sort/scan/placement needed — aggregation is order-independent (LDS accumulators).
__global__ __launch_bounds__(256)
void k_compact(const uint* __restrict__ binned2, const uchar* __restrict__ sBin2,
               const int* __restrict__ localOffR, const int* __restrict__ localOffS,
               const int* __restrict__ rBase,
               float* __restrict__ normS, float* __restrict__ normR,
               uint* __restrict__ sortedSR) {
    __shared__ int cnt[128], cntS2[128];
    __shared__ int cursor;
    const int b = blockIdx.x, t = threadIdx.x;
    const int e0 = rBase[b];
    if (t < 128) { cnt[t] = 0; cntS2[t] = 0; }
    if (t == 0) cursor = 0;
    __syncthreads();
    for (int blk = t; blk < BBLK; blk += 256) {
        size_t base = (size_t)blk * (NBUCK + 1) + b;
        int o0 = localOffR[base], o1 = localOffR[base + 1];
        int len = o1 - o0;
        if (len > 0) {
            int pos = atomicAdd(&cursor, len);
            const uint* src = binned2 + (size_t)blk * EPB + o0;
            for (int i = 0; i < len; ++i) {
                uint v = src[i];
                atomicAdd(&cnt[v & 127u], 1);
                sortedSR[e0 + pos + i] = v;
            }
        }
        int so0 = localOffS[base], so1 = localOffS[base + 1];
        const uchar* ssrc = sBin2 + (size_t)blk * EPB;
        for (int i = so0; i < so1; ++i) atomicAdd(&cntS2[(int)ssrc[i]], 1);
    }
    __syncthreads();
    if (t < 128) {
        int node = b * 128 + t;
        if (node < N_NODE) {
            normR[node] = rsqrtf(fmaxf((float)cnt[t], 1.0f));
            normS[node] = rsqrtf(fmaxf((float)cntS2[t], 1.0f));
        }
    }
}

// ---------------- weight prep: Wt[col][k] = bf16(W[k][col]) ----------------

__global__ __launch_bounds__(256)
void k_prepw(const float* __restrict__ W1, const float* __restrict__ W2,
             const float* __restrict__ W3,
             ushort_t* __restrict__ Wt1, ushort_t* __restrict__ Wt2,
             ushort_t* __restrict__ Wt3) {
    int i = blockIdx.x * 256 + threadIdx.x;
    if (i < 8192) {
        int col = i >> 7, k = i & 127;
        Wt1[i] = bf16r(W1[k * 64 + col]);
    } else if (i < 12288) {
        int j = i - 8192; int col = j >> 6, k = j & 63;
        Wt2[j] = bf16r(W2[k * 64 + col]);
    } else if (i < 14336) {
        int j = i - 12288; int col = j >> 6, k = j & 63;
        Wt3[j] = bf16r(W3[k * 32 + col]);
    }
}

// ---------------- MFMA dense transform: 256 nodes/block (4 M-tiles per wave) ----------------

template<int K, int N, bool F32IN>
__global__ __launch_bounds__(256)
void k_mgemm(const void* __restrict__ Xv, const ushort_t* __restrict__ Wt,
             const float* __restrict__ bias, const float* __restrict__ normS,
             uint* __restrict__ Y2) {
    __shared__ uint WL[N * K / 2];
    const int tid = threadIdx.x, wave = tid >> 6, lane = tid & 63;
    const uint* Wg = (const uint*)Wt;
    for (int i = tid; i < N * K / 2; i += 256) {
        int col = i / (K / 2);
        WL[i ^ ((col & 7) << 2)] = Wg[i];
    }
    __syncthreads();
    const int koff = (lane >> 4) * 8;
    #pragma unroll
    for (int rep = 0; rep < 4; ++rep) {
        const int m0 = blockIdx.x * 256 + rep * 64 + wave * 16;
        const int arow = m0 + (lane & 15);
        const int asrc = (arow < N_NODE) ? arow : 0;
        bf16x8 afr[K / 32];
        if (F32IN) {
            const float* Xf = (const float*)Xv + (size_t)asrc * K + koff;
            #pragma unroll
            for (int s = 0; s < K / 32; ++s) {
                float4 u = *(const float4*)(Xf + 32 * s);
                float4 v = *(const float4*)(Xf + 32 * s + 4);
                union { uint u4[4]; bf16x8 v8; } c;
                c.u4[0] = bfpack(u.x, u.y); c.u4[1] = bfpack(u.z, u.w);
                c.u4[2] = bfpack(v.x, v.y); c.u4[3] = bfpack(v.z, v.w);
                afr[s] = c.v8;
            }
        } else {
            const uint* Xp = (const uint*)Xv + (size_t)asrc * (K / 2) + (koff >> 1);
            #pragma unroll
            for (int s = 0; s < K / 32; ++s) {
                uint2 q0 = *(const uint2*)(Xp + 16 * s);
                uint2 q1 = *(const uint2*)(Xp + 16 * s + 2);
                union { uint u4[4]; bf16x8 v8; } c;
                c.u4[0] = q0.x; c.u4[1] = q0.y; c.u4[2] = q1.x; c.u4[3] = q1.y;
                afr[s] = c.v8;
            }
        }
        f32x4 acc[N / 16];
        #pragma unroll
        for (int t2 = 0; t2 < N / 16; ++t2) acc[t2] = (f32x4){0.f, 0.f, 0.f, 0.f};
        #pragma unroll
        for (int s = 0; s < K / 32; ++s) {
            #pragma unroll
            for (int t2 = 0; t2 < N / 16; ++t2) {
                int col = t2 * 16 + (lane & 15);
                int word = (col * (K / 2) + s * 16 + (koff >> 1)) ^ ((col & 7) << 2);
                bf16x8 bfr = *(const bf16x8*)&WL[word];
                acc[t2] = __builtin_amdgcn_mfma_f32_16x16x32_bf16(afr[s], bfr, acc[t2], 0, 0, 0);
            }
        }
        const int r0 = m0 + (lane >> 4) * 4;
        float ns[4];
        #pragma unroll
        for (int i = 0; i < 4; ++i) ns[i] = (r0 + i < N_NODE) ? normS[r0 + i] : 0.f;
        #pragma unroll
        for (int t2 = 0; t2 < N / 16; ++t2) {
            int col = t2 * 16 + (lane & 15);
            float bv = bias[col];
            #pragma unroll
            for (int i = 0; i < 4; ++i) {
                float v = (acc[t2][i] + bv) * ns[i];
                float w = __shfl_down(v, 1);
                if ((lane & 1) == 0 && r0 + i < N_NODE)
                    Y2[(size_t)(r0 + i) * (N / 2) + (col >> 1)] = bfpack(v, w);
            }
        }
    }
}

// ---------------- aggregation: bucket-stream with LDS fp32 accumulators ----------------
// block = receiver bucket; edges consumed as dense stream of packed (s<<7)|r7 words;
// uint4 gathers; accumulation via LDS atomicAdd into padded [128][2*F2U+2] fp32 tile.

template<int F2U, bool RELU>     // F2U = uints per H row (32 for F=64, 16 for F=32)
__global__ __launch_bounds__(256)
void k_aggb(const uint* __restrict__ H2, const uint* __restrict__ sortedSR,
            const int* __restrict__ rBase, const float* __restrict__ normR,
            uint* __restrict__ Y2) {
    const int ROWF = 2 * F2U + 2;               // padded floats per node (66 / 34)
    __shared__ float acc[128 * ROWF];
    const int b = blockIdx.x, t = threadIdx.x;
    const int lane = t & 63, wave = t >> 6;
    for (int i = t; i < 128 * ROWF; i += 256) acc[i] = 0.f;
    __syncthreads();
    const int e0 = rBase[b], m = rBase[b + 1] - e0;
    const int LPE = F2U / 4;                    // lanes per edge (8 / 4)
    const int EPI = 64 / LPE;                   // edges per wave-instr (8 / 16)
    const int es = lane / LPE;
    const int q  = lane % LPE;
    int i0 = wave * EPI;
    // unroll-2 main loop (both sub-iterations fully active)
    for (; i0 + 3 * EPI + EPI <= m; i0 += 8 * EPI) {
        uint w0 = sortedSR[e0 + i0 + es];
        uint w1 = sortedSR[e0 + i0 + 4 * EPI + es];
        int s0 = (int)(w0 >> 7), r70 = (int)(w0 & 127u);
        int s1 = (int)(w1 >> 7), r71 = (int)(w1 & 127u);
        uint4 v0 = *(const uint4*)&H2[(size_t)s0 * F2U + q * 4];
        uint4 v1 = *(const uint4*)&H2[(size_t)s1 * F2U + q * 4];
        float* a0 = &acc[r70 * ROWF + q * 8];
        atomicAdd(a0 + 0, bflo(v0.x)); atomicAdd(a0 + 1, bfhi(v0.x));
        atomicAdd(a0 + 2, bflo(v0.y)); atomicAdd(a0 + 3, bfhi(v0.y));
        atomicAdd(a0 + 4, bflo(v0.z)); atomicAdd(a0 + 5, bfhi(v0.z));
        atomicAdd(a0 + 6, bflo(v0.w)); atomicAdd(a0 + 7, bfhi(v0.w));
        float* a1 = &acc[r71 * ROWF + q * 8];
        atomicAdd(a1 + 0, bflo(v1.x)); atomicAdd(a1 + 1, bfhi(v1.x));
        atomicAdd(a1 + 2, bflo(v1.y)); atomicAdd(a1 + 3, bfhi(v1.y));
        atomicAdd(a1 + 4, bflo(v1.z)); atomicAdd(a1 + 5, bfhi(v1.z));
        atomicAdd(a1 + 6, bflo(v1.w)); atomicAdd(a1 + 7, bfhi(v1.w));
    }
    for (; i0 < m; i0 += 4 * EPI) {
        int i = i0 + es;
        if (i < m) {
            uint w = sortedSR[e0 + i];
            int s = (int)(w >> 7), r7 = (int)(w & 127u);
            uint4 v = *(const uint4*)&H2[(size_t)s * F2U + q * 4];
            float* ar = &acc[r7 * ROWF + q * 8];
            atomicAdd(ar + 0, bflo(v.x)); atomicAdd(ar + 1, bfhi(v.x));
            atomicAdd(ar + 2, bflo(v.y)); atomicAdd(ar + 3, bfhi(v.y));
            atomicAdd(ar + 4, bflo(v.z)); atomicAdd(ar + 5, bfhi(v.z));
            atomicAdd(ar + 6, bflo(v.w)); atomicAdd(ar + 7, bfhi(v.w));
        }
    }
    __syncthreads();
    const int nbase = b * 128;
    for (int i = t; i < 128 * F2U; i += 256) {
        int r = i / F2U, qq = i % F2U;
        int node = nbase + r;
        if (node < N_NODE) {
            float nr = normR[node];
            float x0 = acc[r * ROWF + 2 * qq] * nr;
            float x1 = acc[r * ROWF + 2 * qq + 1] * nr;
            if (RELU) { x0 = fmaxf(x0, 0.f); x1 = fmaxf(x1, 0.f); }
            Y2[(size_t)node * F2U + qq] = bfpack(x0, x1);
        }
    }
}

// ---------------- graph pooling (batch sorted -> run-based accumulation) ----------------

__global__ __launch_bounds__(256)
void k_pool(const uint* __restrict__ H2, const int* __restrict__ batch,
            float* __restrict__ out) {
    const int wid = (blockIdx.x * 256 + threadIdx.x) >> 6;
    const int lane = threadIdx.x & 63;
    const int NPW = (N_NODE + 1023) / 1024;
    int n0 = wid * NPW, n1 = min(n0 + NPW, N_NODE);
    const int p = lane >> 4, fj = lane & 15;
    float a0 = 0.0f, a1 = 0.0f;
    int gCur = -1;
    for (int n = n0 + p; n < n1; n += 4) {
        int g = batch[n];
        uint v = H2[n * 16 + fj];
        if (g != gCur) {
            if (gCur >= 0) {
                atomicAdd(&out[gCur * OUT_DIM + 2 * fj], a0);
                atomicAdd(&out[gCur * OUT_DIM + 2 * fj + 1], a1);
            }
            gCur = g; a0 = bflo(v); a1 = bfhi(v);
        } else {
            a0 += bflo(v); a1 += bfhi(v);
        }
    }
    if (gCur >= 0) {
        atomicAdd(&out[gCur * OUT_DIM + 2 * fj], a0);
        atomicAdd(&out[gCur * OUT_DIM + 2 * fj + 1], a1);
    }
}

// ---------------- launch ----------------

extern "C" void kernel_launch(void* const* d_in, const int* in_sizes, int n_in,
                              void* d_out, int out_size, void* d_ws, size_t ws_size,
                              hipStream_t stream) {
    const float* x   = (const float*)d_in[0];
    const float* W1  = (const float*)d_in[1];
    const float* b1  = (const float*)d_in[2];
    const float* W2  = (const float*)d_in[3];
    const float* b2  = (const float*)d_in[4];
    const float* W3  = (const float*)d_in[5];
    const float* b3  = (const float*)d_in[6];
    const int* snd   = (const int*)d_in[7];
    const int* rcv   = (const int*)d_in[8];
    const int* batch = (const int*)d_in[9];
    float* out = (float*)d_out;

    char* ws = (char*)d_ws;
    size_t off = 0;
    auto carve = [&](size_t bytes) { char* p = ws + off; off += (bytes + 15) & ~size_t(15); return p; };
    int*   localOffR   = (int*)  carve((size_t)BBLK * (NBUCK + 1) * 4);
    int*   localOffS   = (int*)  carve((size_t)BBLK * (NBUCK + 1) * 4);
    int*   rTotal      = (int*)  carve(NBUCK * 4);
    int*   rBase       = (int*)  carve((NBUCK + 1) * 4);
    uint*  binned2     = (uint*) carve((size_t)N_EDGE * 4);
    uint*  sBin2u      = (uint*) carve((size_t)N_EDGE);
    uint*  sortedSR    = (uint*) carve((size_t)N_EDGE * 4);
    float* normS       = (float*)carve(N_NODE * 4);
    float* normR       = (float*)carve(N_NODE * 4);
    ushort_t* Wt1      = (ushort_t*)carve(8192 * 2);
    ushort_t* Wt2      = (ushort_t*)carve(4096 * 2);
    ushort_t* Wt3      = (ushort_t*)carve(2048 * 2);
    uint*  bufA        = (uint*) carve((size_t)N_NODE * 32 * 4);
    uint*  bufB        = (uint*) carve((size_t)N_NODE * 32 * 4);

    hipMemsetAsync(d_out, 0, NUM_GRAPHS * OUT_DIM * 4, stream);

    k_prepw<<<56, 256, 0, stream>>>(W1, W2, W3, Wt1, Wt2, Wt3);
    k_place2<<<BBLK, 256, 0, stream>>>((const int2*)snd, (const int2*)rcv,
                                       localOffR, localOffS, binned2, sBin2u);
    k_totals<<<NBUCK, 256, 0, stream>>>(localOffR, rTotal);
    k_scanB<<<1, 256, 0, stream>>>(rTotal, rBase);
    k_compact<<<NBUCK, 256, 0, stream>>>(binned2, (const uchar*)sBin2u,
                                         localOffR, localOffS, rBase,
                                         normS, normR, sortedSR);

    const int GB = (N_NODE + 255) / 256;           // 391 gemm blocks (256 nodes each)

    // layer 1: 128 -> 64, relu
    k_mgemm<IN_DIM, HID1, true><<<GB, 256, 0, stream>>>(x, Wt1, b1, normS, bufA);
    k_aggb<32, true><<<NBUCK, 256, 0, stream>>>(bufA, sortedSR, rBase, normR, bufB);

    // layer 2: 64 -> 64, relu
    k_mgemm<HID1, HID2, false><<<GB, 256, 0, stream>>>(bufB, Wt2, b2, normS, bufA);
    k_aggb<32, true><<<NBUCK, 256, 0, stream>>>(bufA, sortedSR, rBase, normR, bufB);

    // layer 3: 64 -> 32, no relu
    k_mgemm<HID2, OUT_DIM, false><<<GB, 256, 0, stream>>>(bufB, Wt3, b3, normS, bufA);
    k_aggb<16, false><<<NBUCK, 256, 0, stream>>>(bufA, sortedSR, rBase, normR, bufB);

    // pooling
    k_pool<<<256, 256, 0, stream>>>(bufB, batch, out);
}